// Round 1
// baseline (1242.051 us; speedup 1.0000x reference)
//
#include <hip/hip_runtime.h>

// BiLSTM: B=512, T=200, E=H=128, 2 layers, bidirectional, residual on layer 1,
// output = 0.5*(fw+bw).  Pipeline:
//   gemm_zx<float>(x)   -> zx[2][M][512] fp16        (fp16 MFMA, bias folded)
//   scan<0>             -> h0f/h0b [M][128] fp16     (dot2 recurrence, fp32 gates)
//   gemm_zx<f16>(h0)    -> zx (reused)
//   scan<1>             -> atomicAdd 0.5*(h1+h0) into zeroed d_out

typedef _Float16 f16;
typedef _Float16 f16x2 __attribute__((ext_vector_type(2)));
typedef _Float16 f16x8 __attribute__((ext_vector_type(8)));
typedef float    f32x4 __attribute__((ext_vector_type(4)));

#define B_   512
#define T_   200
#define E_   128
#define H_   128
#define G4_  512
#define M_   (B_*T_)   // 102400

static __device__ __forceinline__ float fdot2(f16x2 a, f16x2 b, float c) {
#if __has_builtin(__builtin_amdgcn_fdot2)
  return __builtin_amdgcn_fdot2(a, b, c, false);
#else
  return c + (float)a[0]*(float)b[0] + (float)a[1]*(float)b[1];
#endif
}
static __device__ __forceinline__ f16x2 asf2(unsigned int v) { return __builtin_bit_cast(f16x2, v); }
static __device__ __forceinline__ float h2f(unsigned short v) { return (float)__builtin_bit_cast(f16, v); }
static __device__ __forceinline__ float sigm(float x) { return 1.f / (1.f + __expf(-x)); }
static __device__ __forceinline__ float tanh_(float x) { return 2.f / (1.f + __expf(-2.f * x)) - 1.f; }

// ---------------- GEMM: zx[dir][m][g] = A[m][:] @ W[dir][:][g] + b[dir][g] ----------------
// grid (M/128, 512/64, 2), block 256.  Tile 128(M) x 64(N), K=128 single-shot in LDS (fp16).
template <typename AT>
__global__ __launch_bounds__(256)
void gemm_zx(const AT* __restrict__ A0, const AT* __restrict__ A1,
             const float* __restrict__ Wl,   // [2][128][512] (this layer)
             const float* __restrict__ bl,   // [2][512]
             f16* __restrict__ zx)           // [2][M][512]
{
  __shared__ f16 Ash[128 * 136];   // pad to stride 136 halves (272B) -> 2-way banks on b128
  __shared__ f16 Bsh[64 * 136];    // stored transposed: [n][k]

  const int m0  = blockIdx.x * 128;
  const int n0  = blockIdx.y * 64;
  const int dir = blockIdx.z;
  const AT* A = dir ? A1 : A0;
  const float* Wd = Wl + (size_t)dir * E_ * G4_;
  const float* bd = bl + dir * G4_;
  const int tid = threadIdx.x;

  // stage A: 128 rows x 128 k
#pragma unroll
  for (int it = 0; it < 16; ++it) {
    int idx = tid + it * 256;            // 0..4095 float4-slots
    int row = idx >> 5, c4 = idx & 31;   // k = c4*4
    if constexpr (sizeof(AT) == 4) {
      const float4 v = *(const float4*)(A + (size_t)(m0 + row) * E_ + c4 * 4);
      f16x2 p0; p0[0] = (f16)v.x; p0[1] = (f16)v.y;
      f16x2 p1; p1[0] = (f16)v.z; p1[1] = (f16)v.w;
      uint2 w2; w2.x = __builtin_bit_cast(unsigned int, p0); w2.y = __builtin_bit_cast(unsigned int, p1);
      *(uint2*)&Ash[row * 136 + c4 * 4] = w2;
    } else {
      const uint2 v = *(const uint2*)(A + (size_t)(m0 + row) * E_ + c4 * 4);
      *(uint2*)&Ash[row * 136 + c4 * 4] = v;
    }
  }
  // stage B transposed: W[k][n0+n] -> Bsh[n][k]
#pragma unroll
  for (int it = 0; it < 8; ++it) {
    int idx = tid + it * 256;            // 0..2047
    int k = idx >> 4, n4 = idx & 15;
    const float4 v = *(const float4*)(Wd + (size_t)k * G4_ + n0 + n4 * 4);
    Bsh[(n4 * 4 + 0) * 136 + k] = (f16)v.x;
    Bsh[(n4 * 4 + 1) * 136 + k] = (f16)v.y;
    Bsh[(n4 * 4 + 2) * 136 + k] = (f16)v.z;
    Bsh[(n4 * 4 + 3) * 136 + k] = (f16)v.w;
  }
  __syncthreads();

  const int w = tid >> 6, l = tid & 63;
  const int lr = l & 15, lk = (l >> 4) * 8;
  f32x4 acc[2][4] = {};

#pragma unroll
  for (int kc = 0; kc < 4; ++kc) {
    const int kb = kc * 32 + lk;
    f16x8 a0 = *(const f16x8*)&Ash[(w * 32 + 0  + lr) * 136 + kb];
    f16x8 a1 = *(const f16x8*)&Ash[(w * 32 + 16 + lr) * 136 + kb];
    f16x8 b0 = *(const f16x8*)&Bsh[(0  + lr) * 136 + kb];
    f16x8 b1 = *(const f16x8*)&Bsh[(16 + lr) * 136 + kb];
    f16x8 b2 = *(const f16x8*)&Bsh[(32 + lr) * 136 + kb];
    f16x8 b3 = *(const f16x8*)&Bsh[(48 + lr) * 136 + kb];
    acc[0][0] = __builtin_amdgcn_mfma_f32_16x16x32_f16(a0, b0, acc[0][0], 0, 0, 0);
    acc[0][1] = __builtin_amdgcn_mfma_f32_16x16x32_f16(a0, b1, acc[0][1], 0, 0, 0);
    acc[0][2] = __builtin_amdgcn_mfma_f32_16x16x32_f16(a0, b2, acc[0][2], 0, 0, 0);
    acc[0][3] = __builtin_amdgcn_mfma_f32_16x16x32_f16(a0, b3, acc[0][3], 0, 0, 0);
    acc[1][0] = __builtin_amdgcn_mfma_f32_16x16x32_f16(a1, b0, acc[1][0], 0, 0, 0);
    acc[1][1] = __builtin_amdgcn_mfma_f32_16x16x32_f16(a1, b1, acc[1][1], 0, 0, 0);
    acc[1][2] = __builtin_amdgcn_mfma_f32_16x16x32_f16(a1, b2, acc[1][2], 0, 0, 0);
    acc[1][3] = __builtin_amdgcn_mfma_f32_16x16x32_f16(a1, b3, acc[1][3], 0, 0, 0);
  }

  // epilogue: C/D layout col = lane&15, row = (lane>>4)*4 + i  (verified m89)
#pragma unroll
  for (int mf = 0; mf < 2; ++mf) {
#pragma unroll
    for (int nf = 0; nf < 4; ++nf) {
      const int g = n0 + nf * 16 + lr;
      const float bias = bd[g];
#pragma unroll
      for (int i = 0; i < 4; ++i) {
        const int m = m0 + w * 32 + mf * 16 + (l >> 4) * 4 + i;
        zx[((size_t)dir * M_ + m) * G4_ + g] = (f16)(acc[mf][nf][i] + bias);
      }
    }
  }
}

// ---------------- Recurrent scan ----------------
// grid 512 (dir = bx>>8, rowpair = bx&255), block 512.
// Thread t owns gate-column t: U[:,t] lives in 64 packed-fp16 VGPRs.
// Per step: z[r][t] = zx + h[r][:]•U[:,t] via v_dot2_f32_f16 (h broadcast from LDS),
// then 256 threads do gates/cell update in fp32.
template <int LAYER>
__global__ __launch_bounds__(512, 2)
void scan_lstm(const f16* __restrict__ zx,   // [2][M][512]
               const float* __restrict__ Ul, // [2][128][512] (this layer)
               const f16* __restrict__ resf, const f16* __restrict__ resb, // LAYER==1 residual in
               f16* __restrict__ houtf, f16* __restrict__ houtb,           // LAYER==0 out
               float* __restrict__ out)                                    // LAYER==1 out (zeroed)
{
  __shared__ _Float16 hsh[2][128];
  __shared__ float    zsh[2][512];

  const int bx  = blockIdx.x;
  const int dir = bx >> 8;
  const int R0  = (bx & 255) * 2;
  const int t   = threadIdx.x;       // 0..511 == gate column
  const float* Ud = Ul + (size_t)dir * H_ * G4_;
  const f16*  zxd = zx + (size_t)dir * M_ * G4_;

  // U column -> registers, packed fp16 pairs (k, k+1)
  unsigned int ureg[64];
#pragma unroll
  for (int q = 0; q < 64; ++q) {
    float u0 = Ud[(size_t)(2 * q)     * G4_ + t];
    float u1 = Ud[(size_t)(2 * q + 1) * G4_ + t];
    f16x2 p; p[0] = (f16)u0; p[1] = (f16)u1;
    ureg[q] = __builtin_bit_cast(unsigned int, p);
  }

  const int r = t >> 7, j = t & 127;      // valid for t<256 (gate phase)
  const int Rg = R0 + r;
  float c = 0.f;

  if (t < 128) { hsh[0][t] = (f16)0.f; hsh[1][t] = (f16)0.f; }
  __syncthreads();

  int time = dir ? (T_ - 1) : 0;
  const int tstep = dir ? -1 : 1;

  for (int s = 0; s < T_; ++s, time += tstep) {
    // prefetch this step's zx (+residual) for the gate phase; consumed after barrier
    unsigned short rz0 = 0, rz1 = 0, rz2 = 0, rz3 = 0, rres = 0;
    if (t < 256) {
      const unsigned short* zp =
          (const unsigned short*)(zxd + ((size_t)Rg * T_ + time) * G4_) + j;
      rz0 = zp[0]; rz1 = zp[128]; rz2 = zp[256]; rz3 = zp[384];
      if (LAYER == 1) {
        const f16* hp = (dir ? resb : resf) + ((size_t)Rg * T_ + time) * H_ + j;
        rres = *(const unsigned short*)hp;
      }
    }

    // dot phase: all 512 threads, 2 rows x 128 k
    float a0 = 0.f, a1 = 0.f;
#pragma unroll
    for (int q = 0; q < 16; ++q) {
      const uint4 hv0 = *(const uint4*)&hsh[0][q * 8];
      const uint4 hv1 = *(const uint4*)&hsh[1][q * 8];
      a0 = fdot2(asf2(hv0.x), asf2(ureg[q * 4 + 0]), a0);
      a1 = fdot2(asf2(hv1.x), asf2(ureg[q * 4 + 0]), a1);
      a0 = fdot2(asf2(hv0.y), asf2(ureg[q * 4 + 1]), a0);
      a1 = fdot2(asf2(hv1.y), asf2(ureg[q * 4 + 1]), a1);
      a0 = fdot2(asf2(hv0.z), asf2(ureg[q * 4 + 2]), a0);
      a1 = fdot2(asf2(hv1.z), asf2(ureg[q * 4 + 2]), a1);
      a0 = fdot2(asf2(hv0.w), asf2(ureg[q * 4 + 3]), a0);
      a1 = fdot2(asf2(hv1.w), asf2(ureg[q * 4 + 3]), a1);
    }
    zsh[0][t] = a0;
    zsh[1][t] = a1;
    __syncthreads();

    // gate phase: 256 threads = 2 rows x 128 cells
    if (t < 256) {
      const float zi = h2f(rz0) + zsh[r][j];
      const float zf = h2f(rz1) + zsh[r][j + 128];
      const float zg = h2f(rz2) + zsh[r][j + 256];
      const float zo = h2f(rz3) + zsh[r][j + 384];
      const float ig = sigm(zi);
      const float fg = sigm(zf);
      const float gg = tanh_(zg);
      const float og = sigm(zo);
      c = fg * c + ig * gg;
      const float h = og * tanh_(c);
      hsh[r][j] = (f16)h;
      const size_t oidx = ((size_t)Rg * T_ + time) * H_ + j;
      if (LAYER == 0) {
        (dir ? houtb : houtf)[oidx] = (f16)h;
      } else {
        atomicAdd(out + oidx, 0.5f * (h + h2f(rres)));
      }
    }
    __syncthreads();
  }
}

extern "C" void kernel_launch(void* const* d_in, const int* in_sizes, int n_in,
                              void* d_out, int out_size, void* d_ws, size_t ws_size,
                              hipStream_t stream) {
  const float* x = (const float*)d_in[0];
  const float* W = (const float*)d_in[1];  // [2][2][128][512]
  const float* U = (const float*)d_in[2];  // [2][2][128][512]
  const float* b = (const float*)d_in[3];  // [2][2][512]
  float* out = (float*)d_out;

  char* ws = (char*)d_ws;
  f16* zx  = (f16*)ws;                                    // 2*M*512*2 = 209,715,200 B
  f16* h0f = (f16*)(ws + (size_t)2 * M_ * G4_ * 2);       // 26,214,400 B
  f16* h0b = h0f + (size_t)M_ * H_;                       // 26,214,400 B

  hipMemsetAsync(d_out, 0, (size_t)out_size * sizeof(float), stream);

  const size_t WLAYER = (size_t)2 * E_ * G4_;   // 131072 floats
  const size_t BLAYER = 2 * G4_;                // 1024 floats

  dim3 gg(M_ / 128, G4_ / 64, 2);
  // layer 0
  gemm_zx<float><<<gg, 256, 0, stream>>>(x, x, W, b, zx);
  scan_lstm<0><<<dim3(512), 512, 0, stream>>>(zx, U, nullptr, nullptr, h0f, h0b, nullptr);
  // layer 1 (residual layer)
  gemm_zx<f16><<<gg, 256, 0, stream>>>(h0f, h0b, W + WLAYER, b + BLAYER, zx);
  scan_lstm<1><<<dim3(512), 512, 0, stream>>>(zx, U + WLAYER, h0f, h0b, nullptr, nullptr, out);
}

// Round 2
// 1088.200 us; speedup vs baseline: 1.1414x; 1.1414x over previous
//
#include <hip/hip_runtime.h>

// BiLSTM: B=512, T=200, E=H=128, 2 layers, bidirectional, residual on layer 1,
// output = 0.5*(fw+bw).  Pipeline:
//   gemm_zx<float>(x)   -> zx[2][M][512] fp16        (fp16 MFMA, bias folded)
//   scan<0>             -> h0[2][M][128] fp16        (MFMA recurrence)
//   gemm_zx<f16>(h0)    -> zx (reused)
//   scan<1>             -> atomicAdd 0.5*(h1+h0) into zeroed d_out
//
// Scan design (round 2): z^T = U^T (stationary A-frags, 64 VGPR) x h^T (B from
// LDS, 4x ds_read_b128/wave/step vs 32 before -> kills the LDS-pipe bound).
// Wave w owns gate-cols {g*128 + w*16 + c} so each lane holds all 4 gates for
// 4 cells x 1 row in registers; c-state never leaves VGPRs. 16 rows/block,
// 64 blocks, 1 barrier/step, zx staged via global_load_lds one step ahead.

typedef _Float16 f16;
typedef _Float16 f16x2 __attribute__((ext_vector_type(2)));
typedef _Float16 f16x4 __attribute__((ext_vector_type(4)));
typedef _Float16 f16x8 __attribute__((ext_vector_type(8)));
typedef float    f32x4 __attribute__((ext_vector_type(4)));

#define B_   512
#define T_   200
#define E_   128
#define H_   128
#define G4_  512
#define M_   (B_*T_)   // 102400

static __device__ __forceinline__ float rcpf_(float x) {
#if __has_builtin(__builtin_amdgcn_rcpf)
  return __builtin_amdgcn_rcpf(x);
#else
  return 1.f / x;
#endif
}
static __device__ __forceinline__ float sigm(float x) { return rcpf_(1.f + __expf(-x)); }
static __device__ __forceinline__ float tanh_(float x) { return 2.f * rcpf_(1.f + __expf(-2.f * x)) - 1.f; }

static __device__ __forceinline__ void gload_lds16(const void* g, void* l) {
  __builtin_amdgcn_global_load_lds(
      (const __attribute__((address_space(1))) unsigned int*)g,
      (__attribute__((address_space(3))) unsigned int*)l, 16, 0, 0);
}

// ---------------- GEMM: zx[dir][m][g] = A[m][:] @ W[dir][:][g] + b[dir][g] ----------------
// grid (M/128, 512/64, 2), block 256.  Tile 128(M) x 64(N), K=128 single-shot in LDS (fp16).
template <typename AT>
__global__ __launch_bounds__(256)
void gemm_zx(const AT* __restrict__ A0, const AT* __restrict__ A1,
             const float* __restrict__ Wl,   // [2][128][512] (this layer)
             const float* __restrict__ bl,   // [2][512]
             f16* __restrict__ zx)           // [2][M][512]
{
  __shared__ f16 Ash[128 * 136];
  __shared__ f16 Bsh[64 * 136];    // stored transposed: [n][k]

  const int m0  = blockIdx.x * 128;
  const int n0  = blockIdx.y * 64;
  const int dir = blockIdx.z;
  const AT* A = dir ? A1 : A0;
  const float* Wd = Wl + (size_t)dir * E_ * G4_;
  const float* bd = bl + dir * G4_;
  const int tid = threadIdx.x;

#pragma unroll
  for (int it = 0; it < 16; ++it) {
    int idx = tid + it * 256;
    int row = idx >> 5, c4 = idx & 31;
    if constexpr (sizeof(AT) == 4) {
      const float4 v = *(const float4*)(A + (size_t)(m0 + row) * E_ + c4 * 4);
      f16x2 p0; p0[0] = (f16)v.x; p0[1] = (f16)v.y;
      f16x2 p1; p1[0] = (f16)v.z; p1[1] = (f16)v.w;
      uint2 w2; w2.x = __builtin_bit_cast(unsigned int, p0); w2.y = __builtin_bit_cast(unsigned int, p1);
      *(uint2*)&Ash[row * 136 + c4 * 4] = w2;
    } else {
      const uint2 v = *(const uint2*)(A + (size_t)(m0 + row) * E_ + c4 * 4);
      *(uint2*)&Ash[row * 136 + c4 * 4] = v;
    }
  }
#pragma unroll
  for (int it = 0; it < 8; ++it) {
    int idx = tid + it * 256;
    int k = idx >> 4, n4 = idx & 15;
    const float4 v = *(const float4*)(Wd + (size_t)k * G4_ + n0 + n4 * 4);
    Bsh[(n4 * 4 + 0) * 136 + k] = (f16)v.x;
    Bsh[(n4 * 4 + 1) * 136 + k] = (f16)v.y;
    Bsh[(n4 * 4 + 2) * 136 + k] = (f16)v.z;
    Bsh[(n4 * 4 + 3) * 136 + k] = (f16)v.w;
  }
  __syncthreads();

  const int w = tid >> 6, l = tid & 63;
  const int lr = l & 15, lk = (l >> 4) * 8;
  f32x4 acc[2][4] = {};

#pragma unroll
  for (int kc = 0; kc < 4; ++kc) {
    const int kb = kc * 32 + lk;
    f16x8 a0 = *(const f16x8*)&Ash[(w * 32 + 0  + lr) * 136 + kb];
    f16x8 a1 = *(const f16x8*)&Ash[(w * 32 + 16 + lr) * 136 + kb];
    f16x8 b0 = *(const f16x8*)&Bsh[(0  + lr) * 136 + kb];
    f16x8 b1 = *(const f16x8*)&Bsh[(16 + lr) * 136 + kb];
    f16x8 b2 = *(const f16x8*)&Bsh[(32 + lr) * 136 + kb];
    f16x8 b3 = *(const f16x8*)&Bsh[(48 + lr) * 136 + kb];
    acc[0][0] = __builtin_amdgcn_mfma_f32_16x16x32_f16(a0, b0, acc[0][0], 0, 0, 0);
    acc[0][1] = __builtin_amdgcn_mfma_f32_16x16x32_f16(a0, b1, acc[0][1], 0, 0, 0);
    acc[0][2] = __builtin_amdgcn_mfma_f32_16x16x32_f16(a0, b2, acc[0][2], 0, 0, 0);
    acc[0][3] = __builtin_amdgcn_mfma_f32_16x16x32_f16(a0, b3, acc[0][3], 0, 0, 0);
    acc[1][0] = __builtin_amdgcn_mfma_f32_16x16x32_f16(a1, b0, acc[1][0], 0, 0, 0);
    acc[1][1] = __builtin_amdgcn_mfma_f32_16x16x32_f16(a1, b1, acc[1][1], 0, 0, 0);
    acc[1][2] = __builtin_amdgcn_mfma_f32_16x16x32_f16(a1, b2, acc[1][2], 0, 0, 0);
    acc[1][3] = __builtin_amdgcn_mfma_f32_16x16x32_f16(a1, b3, acc[1][3], 0, 0, 0);
  }

#pragma unroll
  for (int mf = 0; mf < 2; ++mf) {
#pragma unroll
    for (int nf = 0; nf < 4; ++nf) {
      const int g = n0 + nf * 16 + lr;
      const float bias = bd[g];
#pragma unroll
      for (int i = 0; i < 4; ++i) {
        const int m = m0 + w * 32 + mf * 16 + (l >> 4) * 4 + i;
        zx[((size_t)dir * M_ + m) * G4_ + g] = (f16)(acc[mf][nf][i] + bias);
      }
    }
  }
}

// ---------------- Recurrent scan (MFMA) ----------------
// grid 64: dir = bx>>5, rows [R0, R0+16).  block 512 = 8 waves.
// Wave w computes gate-cols {g*128 + w*16 + c : c in [0,16)} for all 16 rows.
// Lane l: row = l&15, cells (l>>4)*4 + 0..3 of hidden slice [w*16, w*16+16).
template <int LAYER>
__global__ __launch_bounds__(512, 2)
void scan_lstm(const f16* __restrict__ zx,   // [2][M][512]
               const float* __restrict__ Ul, // [2][128][512] (this layer)
               f16* __restrict__ h0,         // [2][M][128]: LAYER0 writes, LAYER1 reads (residual)
               float* __restrict__ out)      // LAYER1: zeroed accum target
{
  __shared__ f16 hsh[2][16][136];   // stride 136 halves = 272B (16B-aligned, bank-rotated)
  __shared__ f16 zxsh[2][16][516];  // stride 516 halves = 1032B; staged rows are 1024B linear

  const int tid  = threadIdx.x;
  const int lane = tid & 63;
  const int wv   = tid >> 6;        // 0..7
  const int row  = lane & 15;       // batch-row local
  const int kg   = lane >> 4;       // 0..3
  const int bx   = blockIdx.x;
  const int dir  = bx >> 5;
  const int R0   = (bx & 31) * 16;

  const float* Ud  = Ul + (size_t)dir * H_ * G4_;
  const f16* zxd   = zx + (size_t)dir * M_ * G4_;
  f16* h0d         = h0 + (size_t)dir * M_ * H_;

  // stationary A-frags: a[g][kk] = U^T fragment. lane l holds
  // A[gatecol = g*128 + wv*16 + row][k = kk*32 + kg*8 + j], j=0..7
  f16x8 a[4][4];
#pragma unroll
  for (int g = 0; g < 4; ++g) {
    const int gatecol = g * 128 + wv * 16 + row;
#pragma unroll
    for (int kk = 0; kk < 4; ++kk) {
      f16x8 v;
#pragma unroll
      for (int j = 0; j < 8; ++j)
        v[j] = (f16)Ud[(size_t)(kk * 32 + kg * 8 + j) * G4_ + gatecol];
      a[g][kk] = v;
    }
  }

  // zero h state (h(-1) = 0)
  for (int i = tid; i < 2 * 16 * 136; i += 512) ((f16*)hsh)[i] = (f16)0.f;

  float c0 = 0.f, c1 = 0.f, c2 = 0.f, c3 = 0.f;

  const int t0 = dir ? (T_ - 1) : 0;
  const int tstep = dir ? -1 : 1;

  // prologue: stage zx(t0) into zxsh[0]; wave wv stages rows 2wv, 2wv+1
#pragma unroll
  for (int rr = 0; rr < 2; ++rr) {
    const int r = wv * 2 + rr;
    const f16* src = zxd + ((size_t)(R0 + r) * T_ + t0) * G4_;
    gload_lds16((const char*)src + lane * 16, &zxsh[0][r][0]);
  }
  __syncthreads();   // drains vmcnt(0): staging + hsh zero visible

  int p = 0, q = 0;
  for (int s = 0; s < T_; ++s) {
    const int t = t0 + s * tstep;
    const int t2 = (s == T_ - 1) ? t : t + tstep;

    // stage zx(t+1) into zxsh[q^1]
#pragma unroll
    for (int rr = 0; rr < 2; ++rr) {
      const int r = wv * 2 + rr;
      const f16* src = zxd + ((size_t)(R0 + r) * T_ + t2) * G4_;
      gload_lds16((const char*)src + lane * 16, &zxsh[q ^ 1][r][0]);
    }

    // residual prefetch (LAYER1)
    f16x4 rv;
    if (LAYER == 1)
      rv = *(const f16x4*)(h0d + ((size_t)(R0 + row) * T_ + t) * H_ + wv * 16 + kg * 4);

    // z^T = U^T . h^T : B-frag lane l = h[row l&15][k = kk*32 + kg*8 + j]
    f32x4 z0 = {0.f, 0.f, 0.f, 0.f}, z1 = z0, z2 = z0, z3 = z0;
#pragma unroll
    for (int kk = 0; kk < 4; ++kk) {
      const f16x8 bf = *(const f16x8*)&hsh[p][row][kk * 32 + kg * 8];
      z0 = __builtin_amdgcn_mfma_f32_16x16x32_f16(a[0][kk], bf, z0, 0, 0, 0);
      z1 = __builtin_amdgcn_mfma_f32_16x16x32_f16(a[1][kk], bf, z1, 0, 0, 0);
      z2 = __builtin_amdgcn_mfma_f32_16x16x32_f16(a[2][kk], bf, z2, 0, 0, 0);
      z3 = __builtin_amdgcn_mfma_f32_16x16x32_f16(a[3][kk], bf, z3, 0, 0, 0);
    }

    // zx gate values for this lane's 4 cells, all 4 gates (b64 each)
    const f16x4 zqi = *(const f16x4*)&zxsh[q][row][0 * 128 + wv * 16 + kg * 4];
    const f16x4 zqf = *(const f16x4*)&zxsh[q][row][1 * 128 + wv * 16 + kg * 4];
    const f16x4 zqg = *(const f16x4*)&zxsh[q][row][2 * 128 + wv * 16 + kg * 4];
    const f16x4 zqo = *(const f16x4*)&zxsh[q][row][3 * 128 + wv * 16 + kg * 4];

    // gates fully in-register; D row (l>>4)*4+i = cell, col l&15 = batch row
    float hv[4];
    float cc[4] = {c0, c1, c2, c3};
#pragma unroll
    for (int i = 0; i < 4; ++i) {
      const float ig = sigm((float)zqi[i] + z0[i]);
      const float fg = sigm((float)zqf[i] + z1[i]);
      const float gg = tanh_((float)zqg[i] + z2[i]);
      const float og = sigm((float)zqo[i] + z3[i]);
      cc[i] = fg * cc[i] + ig * gg;
      hv[i] = og * tanh_(cc[i]);
    }
    c0 = cc[0]; c1 = cc[1]; c2 = cc[2]; c3 = cc[3];

    // write h(t) to hsh[p^1]
    f16x4 hp;
#pragma unroll
    for (int i = 0; i < 4; ++i) hp[i] = (f16)hv[i];
    *(f16x4*)&hsh[p ^ 1][row][wv * 16 + kg * 4] = hp;

    // global output
    const size_t oidx = ((size_t)(R0 + row) * T_ + t) * H_ + wv * 16 + kg * 4;
    if (LAYER == 0) {
      *(f16x4*)(h0d + oidx) = hp;
    } else {
      float* op = out + oidx;
#pragma unroll
      for (int i = 0; i < 4; ++i)
        atomicAdd(op + i, 0.5f * (hv[i] + (float)rv[i]));
    }

    __syncthreads();   // implicit vmcnt(0)+lgkmcnt(0): t+1 staging + hsh writes done
    p ^= 1; q ^= 1;
  }
}

extern "C" void kernel_launch(void* const* d_in, const int* in_sizes, int n_in,
                              void* d_out, int out_size, void* d_ws, size_t ws_size,
                              hipStream_t stream) {
  const float* x = (const float*)d_in[0];
  const float* W = (const float*)d_in[1];  // [2][2][128][512]
  const float* U = (const float*)d_in[2];  // [2][2][128][512]
  const float* b = (const float*)d_in[3];  // [2][2][512]
  float* out = (float*)d_out;

  char* ws = (char*)d_ws;
  f16* zx = (f16*)ws;                               // 2*M*512*2 = 209,715,200 B
  f16* h0 = (f16*)(ws + (size_t)2 * M_ * G4_ * 2);  // [2][M][128] = 52,428,800 B

  hipMemsetAsync(d_out, 0, (size_t)out_size * sizeof(float), stream);

  const size_t WLAYER = (size_t)2 * E_ * G4_;   // floats per layer of W/U
  const size_t BLAYER = 2 * G4_;

  dim3 gg(M_ / 128, G4_ / 64, 2);
  // layer 0
  gemm_zx<float><<<gg, 256, 0, stream>>>(x, x, W, b, zx);
  scan_lstm<0><<<dim3(64), 512, 0, stream>>>(zx, U, h0, nullptr);
  // layer 1 (residual layer)
  gemm_zx<f16><<<gg, 256, 0, stream>>>(h0, h0 + (size_t)M_ * H_, W + WLAYER, b + BLAYER, zx);
  scan_lstm<1><<<dim3(64), 512, 0, stream>>>(zx, U + WLAYER, h0, out);
}

// Round 3
// 726.617 us; speedup vs baseline: 1.7094x; 1.4976x over previous
//
#include <hip/hip_runtime.h>

// BiLSTM fused: B=512, T=200, E=H=128, 2 layers, bidir, residual on layer 1,
// out = 0.5*(fw+bw).  No precomputed zx: each scan step computes
//   z = W*x(t) + U*h(t-1) + b  entirely with per-wave MFMA:
//     - aW, aU stationary A-frags (64+64 VGPR/lane), bias folded into C-init
//     - x(t) B-frags prefetched into REGISTERS depth-2 (counted vmcnt, no drain)
//     - h exchanged through LDS, raw s_barrier + lgkmcnt(0) only (vmcnt never
//       drained -> HBM latency off the 200-step critical path)
// Layer1 writes 0.5*(h+res) per dir (fp16); final_add sums dirs into d_out.

typedef _Float16 f16;
typedef _Float16 f16x4 __attribute__((ext_vector_type(4)));
typedef _Float16 f16x8 __attribute__((ext_vector_type(8)));
typedef float    f32x4 __attribute__((ext_vector_type(4)));

#define B_   512
#define T_   200
#define E_   128
#define H_   128
#define G4_  512
#define M_   (B_*T_)   // 102400

static __device__ __forceinline__ float rcpf_(float x) {
#if __has_builtin(__builtin_amdgcn_rcpf)
  return __builtin_amdgcn_rcpf(x);
#else
  return 1.f / x;
#endif
}
static __device__ __forceinline__ float sigm(float x) { return rcpf_(1.f + __expf(-x)); }
static __device__ __forceinline__ float tanh_(float x) { return 2.f * rcpf_(1.f + __expf(-2.f * x)) - 1.f; }

static __device__ __forceinline__ void lgkm_barrier() {
  asm volatile("s_waitcnt lgkmcnt(0)" ::: "memory");
  __builtin_amdgcn_s_barrier();
}

// input B-frag pipeline: holds one timestep's x slice for this lane
template <typename AT> struct InPipe;
template <> struct InPipe<float> {
  float4 r[8];
  __device__ __forceinline__ void load(const float* p, int kg) {
#pragma unroll
    for (int kk = 0; kk < 4; ++kk) {
      r[kk * 2]     = *(const float4*)(p + kk * 32 + kg * 8);
      r[kk * 2 + 1] = *(const float4*)(p + kk * 32 + kg * 8 + 4);
    }
  }
  __device__ __forceinline__ void get(f16x8 xf[4]) const {
#pragma unroll
    for (int kk = 0; kk < 4; ++kk) {
      f16x8 v;
      v[0] = (f16)r[kk*2].x;     v[1] = (f16)r[kk*2].y;
      v[2] = (f16)r[kk*2].z;     v[3] = (f16)r[kk*2].w;
      v[4] = (f16)r[kk*2+1].x;   v[5] = (f16)r[kk*2+1].y;
      v[6] = (f16)r[kk*2+1].z;   v[7] = (f16)r[kk*2+1].w;
      xf[kk] = v;
    }
  }
};
template <> struct InPipe<f16> {
  f16x8 r[4];
  __device__ __forceinline__ void load(const f16* p, int kg) {
#pragma unroll
    for (int kk = 0; kk < 4; ++kk) r[kk] = *(const f16x8*)(p + kk * 32 + kg * 8);
  }
  __device__ __forceinline__ void get(f16x8 xf[4]) const {
#pragma unroll
    for (int kk = 0; kk < 4; ++kk) xf[kk] = r[kk];
  }
};

// grid 64: dir = bx>>5, rows [R0, R0+16). block 512 = 8 waves.
// Wave wv owns gate-cols {g*128 + wv*16 + c}.  Lane l: batch row l&15,
// k-group kg=l>>4, output cells kg*4+i of hidden slice [wv*16, wv*16+16).
template <int LAYER, typename AT>
__global__ __launch_bounds__(512, 2)
void scan_fused(const AT* __restrict__ in,    // L0: x [M][128] (both dirs); L1: h0 [2][M][128]
                const float* __restrict__ Ul, // [2][128][512] this layer
                const float* __restrict__ Wl, // [2][128][512] this layer
                const float* __restrict__ bl, // [2][512] this layer
                const f16* __restrict__ res,  // L1: h0 [2][M][128]
                f16* __restrict__ hout)       // [2][M][128]
{
  __shared__ f16 hsh[2][16][136];

  const int tid  = threadIdx.x;
  const int lane = tid & 63;
  const int wv   = tid >> 6;
  const int row  = lane & 15;
  const int kg   = lane >> 4;
  const int bx   = blockIdx.x;
  const int dir  = bx >> 5;
  const int R0   = (bx & 31) * 16;
  const int coff = wv * 16 + kg * 4;

  const float* Ud = Ul + (size_t)dir * H_ * G4_;
  const float* Wd = Wl + (size_t)dir * E_ * G4_;
  const float* bd = bl + (size_t)dir * G4_;
  const AT* ind   = in + (LAYER == 1 ? (size_t)dir * M_ * H_ : 0);
  f16* houtd      = hout + (size_t)dir * M_ * H_;

  // stationary A-frags (U^T and W^T) + bias as MFMA C-init
  f16x8 aU[4][4], aW[4][4];
#pragma unroll
  for (int g = 0; g < 4; ++g) {
    const int gcol = g * 128 + wv * 16 + row;
#pragma unroll
    for (int kk = 0; kk < 4; ++kk) {
      f16x8 vu, vw;
#pragma unroll
      for (int j = 0; j < 8; ++j) {
        const size_t k = (size_t)(kk * 32 + kg * 8 + j);
        vu[j] = (f16)Ud[k * G4_ + gcol];
        vw[j] = (f16)Wd[k * G4_ + gcol];
      }
      aU[g][kk] = vu;
      aW[g][kk] = vw;
    }
  }
  f32x4 zb[4];
#pragma unroll
  for (int g = 0; g < 4; ++g) {
#pragma unroll
    for (int i = 0; i < 4; ++i) zb[g][i] = bd[g * 128 + coff + i];
  }

  // zero h(-1)
  for (int i = tid; i < 2 * 16 * 136; i += 512) ((f16*)hsh)[i] = (f16)0.f;

  const int t0 = dir ? (T_ - 1) : 0;
  const int ts = dir ? -1 : 1;

  const AT*  inrow  = ind + (size_t)(R0 + row) * T_ * E_;
  const f16* resrow = (LAYER == 1) ? res + (size_t)dir * M_ * H_ + (size_t)(R0 + row) * T_ * H_
                                   : nullptr;
  f16* outrow = houtd + (size_t)(R0 + row) * T_ * H_;

  float cc[4] = {0.f, 0.f, 0.f, 0.f};

  // prologue: prefetch t(0), t(1)
  InPipe<AT> xpA, xpB;
  f16x4 rvA = {}, rvB = {};
  xpA.load(inrow + (size_t)t0 * E_, kg);
  xpB.load(inrow + (size_t)(t0 + ts) * E_, kg);
  if (LAYER == 1) {
    rvA = *(const f16x4*)(resrow + (size_t)t0 * H_ + coff);
    rvB = *(const f16x4*)(resrow + (size_t)(t0 + ts) * H_ + coff);
  }

  lgkm_barrier();   // hsh zero visible

  auto step = [&](InPipe<AT>& xp, f16x4& rv, int s, int rp, int wp) {
    const int t = t0 + s * ts;

    f16x8 xf[4];
    xp.get(xf);                       // counted vmcnt wait (issued 2 steps ago)
    float rvf[4];
    if (LAYER == 1) {
#pragma unroll
      for (int i = 0; i < 4; ++i) rvf[i] = (float)rv[i];
    }
    // prefetch t(s+2) into the just-freed pipeline regs
    {
      const int spf = s + 2;
      const size_t tpf = (spf < T_) ? (size_t)(t0 + spf * ts) : (size_t)t0;
      xp.load(inrow + tpf * E_, kg);
      if (LAYER == 1) rv = *(const f16x4*)(resrow + tpf * H_ + coff);
    }

    // z = b + W*x(t) (independent of h -> overlaps the h ds_read latency)
    f32x4 z0 = zb[0], z1 = zb[1], z2 = zb[2], z3 = zb[3];
#pragma unroll
    for (int kk = 0; kk < 4; ++kk) {
      z0 = __builtin_amdgcn_mfma_f32_16x16x32_f16(aW[0][kk], xf[kk], z0, 0, 0, 0);
      z1 = __builtin_amdgcn_mfma_f32_16x16x32_f16(aW[1][kk], xf[kk], z1, 0, 0, 0);
      z2 = __builtin_amdgcn_mfma_f32_16x16x32_f16(aW[2][kk], xf[kk], z2, 0, 0, 0);
      z3 = __builtin_amdgcn_mfma_f32_16x16x32_f16(aW[3][kk], xf[kk], z3, 0, 0, 0);
    }
    // + U*h(t-1)
    f16x8 hf[4];
#pragma unroll
    for (int kk = 0; kk < 4; ++kk) hf[kk] = *(const f16x8*)&hsh[rp][row][kk * 32 + kg * 8];
#pragma unroll
    for (int kk = 0; kk < 4; ++kk) {
      z0 = __builtin_amdgcn_mfma_f32_16x16x32_f16(aU[0][kk], hf[kk], z0, 0, 0, 0);
      z1 = __builtin_amdgcn_mfma_f32_16x16x32_f16(aU[1][kk], hf[kk], z1, 0, 0, 0);
      z2 = __builtin_amdgcn_mfma_f32_16x16x32_f16(aU[2][kk], hf[kk], z2, 0, 0, 0);
      z3 = __builtin_amdgcn_mfma_f32_16x16x32_f16(aU[3][kk], hf[kk], z3, 0, 0, 0);
    }

    // gates (D: row kg*4+i = gate cell, col l&15 = batch row)
    float hv[4];
#pragma unroll
    for (int i = 0; i < 4; ++i) {
      const float ig = sigm(z0[i]);
      const float fg = sigm(z1[i]);
      const float gg = tanh_(z2[i]);
      const float og = sigm(z3[i]);
      cc[i] = fg * cc[i] + ig * gg;
      hv[i] = og * tanh_(cc[i]);
    }
    f16x4 hp;
#pragma unroll
    for (int i = 0; i < 4; ++i) hp[i] = (f16)hv[i];
    *(f16x4*)&hsh[wp][row][coff] = hp;

    f16* orow = outrow + (size_t)t * H_ + coff;
    if (LAYER == 0) {
      *(f16x4*)orow = hp;
    } else {
      f16x4 o;
#pragma unroll
      for (int i = 0; i < 4; ++i) o[i] = (f16)(0.5f * (hv[i] + rvf[i]));
      *(f16x4*)orow = o;
    }

    lgkm_barrier();   // h(t) visible to all waves; vmcnt NOT drained
  };

  for (int k = 0; k < T_ / 2; ++k) {
    step(xpA, rvA, 2 * k,     0, 1);
    step(xpB, rvB, 2 * k + 1, 1, 0);
  }
}

__global__ __launch_bounds__(256)
void final_add(const f16* __restrict__ a, const f16* __restrict__ b,
               float* __restrict__ o)
{
  const int n8 = M_ * H_ / 8;
  for (int i = blockIdx.x * 256 + threadIdx.x; i < n8; i += gridDim.x * 256) {
    const f16x8 va = *(const f16x8*)(a + (size_t)i * 8);
    const f16x8 vb = *(const f16x8*)(b + (size_t)i * 8);
    float4 o0, o1;
    o0.x = (float)va[0] + (float)vb[0];  o0.y = (float)va[1] + (float)vb[1];
    o0.z = (float)va[2] + (float)vb[2];  o0.w = (float)va[3] + (float)vb[3];
    o1.x = (float)va[4] + (float)vb[4];  o1.y = (float)va[5] + (float)vb[5];
    o1.z = (float)va[6] + (float)vb[6];  o1.w = (float)va[7] + (float)vb[7];
    *(float4*)(o + (size_t)i * 8)     = o0;
    *(float4*)(o + (size_t)i * 8 + 4) = o1;
  }
}

extern "C" void kernel_launch(void* const* d_in, const int* in_sizes, int n_in,
                              void* d_out, int out_size, void* d_ws, size_t ws_size,
                              hipStream_t stream) {
  const float* x = (const float*)d_in[0];
  const float* W = (const float*)d_in[1];  // [2][2][128][512]
  const float* U = (const float*)d_in[2];  // [2][2][128][512]
  const float* b = (const float*)d_in[3];  // [2][2][512]
  float* out = (float*)d_out;

  f16* h0 = (f16*)d_ws;                    // [2][M][128] = 52.4 MB
  f16* h1 = h0 + (size_t)2 * M_ * H_;      // [2][M][128] = 52.4 MB

  const size_t WL = (size_t)2 * E_ * G4_;  // floats per layer of W/U
  const size_t BL = 2 * G4_;

  scan_fused<0, float><<<dim3(64), 512, 0, stream>>>(x, U, W, b, nullptr, h0);
  scan_fused<1, f16><<<dim3(64), 512, 0, stream>>>(h0, U + WL, W + WL, b + BL, h0, h1);
  final_add<<<dim3(2048), 256, 0, stream>>>(h1, h1 + (size_t)M_ * H_, out);
}

// Round 4
// 684.782 us; speedup vs baseline: 1.8138x; 1.0611x over previous
//
#include <hip/hip_runtime.h>

// BiLSTM fused: B=512, T=200, E=H=128, 2 layers, bidir, residual on layer 1,
// out = 0.5*(fw+bw).  Each scan step computes z = W*x(t) + U*h(t-1) + b fully
// per-wave-MFMA; h exchanged via LDS with raw s_barrier + lgkmcnt(0) (vmcnt
// never drained).  Round 4: all-f16 inputs (x pre-converted, W/U pre-
// transposed to [gatecol][k] f16) to fit the 256-reg budget without
// AGPR-copy/spill machinery; h ds_reads hoisted to overlap W-MFMAs.

typedef _Float16 f16;
typedef _Float16 f16x4 __attribute__((ext_vector_type(4)));
typedef _Float16 f16x8 __attribute__((ext_vector_type(8)));
typedef float    f32x4 __attribute__((ext_vector_type(4)));

#define B_   512
#define T_   200
#define E_   128
#define H_   128
#define G4_  512
#define M_   (B_*T_)   // 102400

static __device__ __forceinline__ float rcpf_(float x) {
#if __has_builtin(__builtin_amdgcn_rcpf)
  return __builtin_amdgcn_rcpf(x);
#else
  return 1.f / x;
#endif
}
static __device__ __forceinline__ float sigm(float x) { return rcpf_(1.f + __expf(-x)); }
static __device__ __forceinline__ float tanh_(float x) { return 2.f * rcpf_(1.f + __expf(-2.f * x)) - 1.f; }

static __device__ __forceinline__ void lgkm_barrier() {
  asm volatile("s_waitcnt lgkmcnt(0)" ::: "memory");
  __builtin_amdgcn_s_barrier();
}

// ---------- prep: x fp32 -> f16 ----------
__global__ __launch_bounds__(256)
void cvt_x(const float* __restrict__ x, f16* __restrict__ xh) {
  const int n8 = M_ * E_ / 8;
  for (int i = blockIdx.x * 256 + threadIdx.x; i < n8; i += gridDim.x * 256) {
    const float4 a = ((const float4*)x)[i * 2];
    const float4 b = ((const float4*)x)[i * 2 + 1];
    f16x8 v;
    v[0] = (f16)a.x; v[1] = (f16)a.y; v[2] = (f16)a.z; v[3] = (f16)a.w;
    v[4] = (f16)b.x; v[5] = (f16)b.y; v[6] = (f16)b.z; v[7] = (f16)b.w;
    *(f16x8*)(xh + (size_t)i * 8) = v;
  }
}

// ---------- prep: W,U [slab][128][512] fp32 -> [slab][512][128] f16 ----------
// 8 slabs: 4 of W ([L][dir]) then 4 of U.
__global__ __launch_bounds__(256)
void prep_w(const float* __restrict__ W, const float* __restrict__ U,
            f16* __restrict__ Wt, f16* __restrict__ Ut) {
  const int m = blockIdx.x;                     // 0..7
  const float* s = (m < 4 ? W + (size_t)m * E_ * G4_ : U + (size_t)(m - 4) * E_ * G4_);
  f16* d        = (m < 4 ? Wt + (size_t)m * E_ * G4_ : Ut + (size_t)(m - 4) * E_ * G4_);
  for (int i = threadIdx.x; i < E_ * G4_; i += 256) {
    const int k = i >> 9, g = i & 511;
    d[(size_t)g * E_ + k] = (f16)s[i];
  }
}

// ---------- fused recurrent scan ----------
// grid 64: dir = bx>>5, rows [R0, R0+16).  block 512 = 8 waves.
// Wave wv owns gate-cols {g*128 + wv*16 + c}.  Lane l: batch row l&15,
// kg = l>>4, output cells kg*4+i of hidden slice [wv*16, wv*16+16).
template <int LAYER>
__global__ __launch_bounds__(512, 2)
void scan_fused(const f16* __restrict__ in,    // L0: xh [M][128]; L1: h0 [2][M][128]
                const f16* __restrict__ Utl,   // [2][512][128] this layer (transposed)
                const f16* __restrict__ Wtl,   // [2][512][128] this layer (transposed)
                const float* __restrict__ bl,  // [2][512] this layer
                const f16* __restrict__ res,   // L1: h0 [2][M][128]
                f16* __restrict__ hout)        // [2][M][128]
{
  __shared__ f16 hsh[2][16][136];

  const int tid  = threadIdx.x;
  const int lane = tid & 63;
  const int wv   = tid >> 6;
  const int row  = lane & 15;
  const int kg   = lane >> 4;
  const int bx   = blockIdx.x;
  const int dir  = bx >> 5;
  const int R0   = (bx & 31) * 16;
  const int coff = wv * 16 + kg * 4;

  const f16* Ud = Utl + (size_t)dir * G4_ * E_;
  const f16* Wd = Wtl + (size_t)dir * G4_ * E_;
  const float* bd = bl + (size_t)dir * G4_;
  const f16* ind  = in + (LAYER == 1 ? (size_t)dir * M_ * H_ : 0);
  f16* houtd      = hout + (size_t)dir * M_ * H_;

  // stationary A-frags from transposed f16 weights (vector loads)
  f16x8 aU[4][4], aW[4][4];
#pragma unroll
  for (int g = 0; g < 4; ++g) {
    const size_t gcol = (size_t)(g * 128 + wv * 16 + row) * E_;
#pragma unroll
    for (int kk = 0; kk < 4; ++kk) {
      aU[g][kk] = *(const f16x8*)(Ud + gcol + kk * 32 + kg * 8);
      aW[g][kk] = *(const f16x8*)(Wd + gcol + kk * 32 + kg * 8);
    }
  }
  f32x4 zb[4];
#pragma unroll
  for (int g = 0; g < 4; ++g) {
#pragma unroll
    for (int i = 0; i < 4; ++i) zb[g][i] = bd[g * 128 + coff + i];
  }

  // zero h(-1)
  for (int i = tid; i < 2 * 16 * 136; i += 512) ((f16*)hsh)[i] = (f16)0.f;

  const int t0 = dir ? (T_ - 1) : 0;
  const int ts = dir ? -1 : 1;

  const f16* inrow  = ind + (size_t)(R0 + row) * T_ * E_;
  const f16* resrow = (LAYER == 1)
      ? res + (size_t)dir * M_ * H_ + (size_t)(R0 + row) * T_ * H_ : nullptr;
  f16* outrow = houtd + (size_t)(R0 + row) * T_ * H_;

  float cc[4] = {0.f, 0.f, 0.f, 0.f};

  // depth-2 register pipelines for x (and residual)
  f16x8 xA[4], xB[4];
  f16x4 rvA = {}, rvB = {};
  {
    const f16* pA = inrow + (size_t)t0 * E_;
    const f16* pB = inrow + (size_t)(t0 + ts) * E_;
#pragma unroll
    for (int kk = 0; kk < 4; ++kk) {
      xA[kk] = *(const f16x8*)(pA + kk * 32 + kg * 8);
      xB[kk] = *(const f16x8*)(pB + kk * 32 + kg * 8);
    }
    if (LAYER == 1) {
      rvA = *(const f16x4*)(resrow + (size_t)t0 * H_ + coff);
      rvB = *(const f16x4*)(resrow + (size_t)(t0 + ts) * H_ + coff);
    }
  }

  lgkm_barrier();   // hsh zero visible

  auto step = [&](f16x8 (&xp)[4], f16x4& rv, int s, int rp, int wp) {
    const int t = t0 + s * ts;

    // h(t-1) reads first: latency hides under W-MFMAs
    f16x8 hf[4];
#pragma unroll
    for (int kk = 0; kk < 4; ++kk) hf[kk] = *(const f16x8*)&hsh[rp][row][kk * 32 + kg * 8];

    // consume pipeline regs (counted vmcnt wait: issued 2 steps ago)
    f16x8 xf[4];
#pragma unroll
    for (int kk = 0; kk < 4; ++kk) xf[kk] = xp[kk];
    float rvf[4];
    if (LAYER == 1) {
#pragma unroll
      for (int i = 0; i < 4; ++i) rvf[i] = (float)rv[i];
    }

    // prefetch t(s+2)
    {
      const int spf = s + 2;
      const size_t tpf = (spf < T_) ? (size_t)(t0 + spf * ts) : (size_t)t0;
      const f16* p = inrow + tpf * E_;
#pragma unroll
      for (int kk = 0; kk < 4; ++kk) xp[kk] = *(const f16x8*)(p + kk * 32 + kg * 8);
      if (LAYER == 1) rv = *(const f16x4*)(resrow + tpf * H_ + coff);
    }

    // z = b + W*x(t)  (independent of h)
    f32x4 z0 = zb[0], z1 = zb[1], z2 = zb[2], z3 = zb[3];
#pragma unroll
    for (int kk = 0; kk < 4; ++kk) {
      z0 = __builtin_amdgcn_mfma_f32_16x16x32_f16(aW[0][kk], xf[kk], z0, 0, 0, 0);
      z1 = __builtin_amdgcn_mfma_f32_16x16x32_f16(aW[1][kk], xf[kk], z1, 0, 0, 0);
      z2 = __builtin_amdgcn_mfma_f32_16x16x32_f16(aW[2][kk], xf[kk], z2, 0, 0, 0);
      z3 = __builtin_amdgcn_mfma_f32_16x16x32_f16(aW[3][kk], xf[kk], z3, 0, 0, 0);
    }
    // + U*h(t-1)
#pragma unroll
    for (int kk = 0; kk < 4; ++kk) {
      z0 = __builtin_amdgcn_mfma_f32_16x16x32_f16(aU[0][kk], hf[kk], z0, 0, 0, 0);
      z1 = __builtin_amdgcn_mfma_f32_16x16x32_f16(aU[1][kk], hf[kk], z1, 0, 0, 0);
      z2 = __builtin_amdgcn_mfma_f32_16x16x32_f16(aU[2][kk], hf[kk], z2, 0, 0, 0);
      z3 = __builtin_amdgcn_mfma_f32_16x16x32_f16(aU[3][kk], hf[kk], z3, 0, 0, 0);
    }

    // gates (D: row kg*4+i = gate cell, col l&15 = batch row)
    float hv[4];
#pragma unroll
    for (int i = 0; i < 4; ++i) {
      const float ig = sigm(z0[i]);
      const float fg = sigm(z1[i]);
      const float gg = tanh_(z2[i]);
      const float og = sigm(z3[i]);
      cc[i] = fg * cc[i] + ig * gg;
      hv[i] = og * tanh_(cc[i]);
    }
    f16x4 hp;
#pragma unroll
    for (int i = 0; i < 4; ++i) hp[i] = (f16)hv[i];
    // LDS write first so the end-of-step lgkm drain clears asap
    *(f16x4*)&hsh[wp][row][coff] = hp;

    f16* orow = outrow + (size_t)t * H_ + coff;
    if (LAYER == 0) {
      *(f16x4*)orow = hp;
    } else {
      f16x4 o;
#pragma unroll
      for (int i = 0; i < 4; ++i) o[i] = (f16)(0.5f * (hv[i] + rvf[i]));
      *(f16x4*)orow = o;
    }

    lgkm_barrier();   // h(t) visible; vmcnt NOT drained
  };

  for (int k = 0; k < T_ / 2; ++k) {
    step(xA, rvA, 2 * k,     0, 1);
    step(xB, rvB, 2 * k + 1, 1, 0);
  }
}

__global__ __launch_bounds__(256)
void final_add(const f16* __restrict__ a, const f16* __restrict__ b,
               float* __restrict__ o)
{
  const int n8 = M_ * H_ / 8;
  for (int i = blockIdx.x * 256 + threadIdx.x; i < n8; i += gridDim.x * 256) {
    const f16x8 va = *(const f16x8*)(a + (size_t)i * 8);
    const f16x8 vb = *(const f16x8*)(b + (size_t)i * 8);
    float4 o0, o1;
    o0.x = (float)va[0] + (float)vb[0];  o0.y = (float)va[1] + (float)vb[1];
    o0.z = (float)va[2] + (float)vb[2];  o0.w = (float)va[3] + (float)vb[3];
    o1.x = (float)va[4] + (float)vb[4];  o1.y = (float)va[5] + (float)vb[5];
    o1.z = (float)va[6] + (float)vb[6];  o1.w = (float)va[7] + (float)vb[7];
    *(float4*)(o + (size_t)i * 8)     = o0;
    *(float4*)(o + (size_t)i * 8 + 4) = o1;
  }
}

extern "C" void kernel_launch(void* const* d_in, const int* in_sizes, int n_in,
                              void* d_out, int out_size, void* d_ws, size_t ws_size,
                              hipStream_t stream) {
  const float* x = (const float*)d_in[0];
  const float* W = (const float*)d_in[1];  // [2][2][128][512]
  const float* U = (const float*)d_in[2];  // [2][2][128][512]
  const float* b = (const float*)d_in[3];  // [2][2][512]
  float* out = (float*)d_out;

  char* ws = (char*)d_ws;
  f16* xh = (f16*)ws;                              // [M][128]    26.2 MB
  f16* h0 = xh + (size_t)M_ * E_;                  // [2][M][128] 52.4 MB
  f16* h1 = h0 + (size_t)2 * M_ * H_;              // [2][M][128] 52.4 MB
  f16* Wt = h1 + (size_t)2 * M_ * H_;              // [2][2][512][128] 1 MB
  f16* Ut = Wt + (size_t)4 * G4_ * E_;             // [2][2][512][128] 1 MB

  const size_t WTL = (size_t)2 * G4_ * E_;         // f16 per layer of Wt/Ut
  const size_t BL  = 2 * G4_;

  cvt_x<<<dim3(2048), 256, 0, stream>>>(x, xh);
  prep_w<<<dim3(8), 256, 0, stream>>>(W, U, Wt, Ut);
  scan_fused<0><<<dim3(64), 512, 0, stream>>>(xh, Ut, Wt, b, nullptr, h0);
  scan_fused<1><<<dim3(64), 512, 0, stream>>>(h0, Ut + WTL, Wt + WTL, b + BL, h0, h1);
  final_add<<<dim3(2048), 256, 0, stream>>>(h1, h1 + (size_t)M_ * H_, out);
}

// Round 5
// 618.468 us; speedup vs baseline: 2.0083x; 1.1072x over previous
//
#include <hip/hip_runtime.h>
#include <math.h>

// BiLSTM fused: B=512, T=200, E=H=128, 2 layers, bidir, residual on layer 1,
// out = 0.5*(fw+bw).  Per scan step: z = W*x(t) + U*h(t-1) + b all in MFMA;
// h exchanged via LDS with raw s_barrier + lgkmcnt(0) (vmcnt never drained).
// Round 5:
//   - sigma LUT in LDS (8192 entries, [-16,16), NN): all 5 nonlinearities are
//     sigma lookups (tanh = 2*sigma(2x)-1, g-gate weights prescaled x2).
//     Removes ~40 transcendentals/lane-step from the VALU pipe.
//   - cross-step overlap: while gates(z(t)) run, the h-independent
//     z(t+1) = b + W*x(t+1) MFMAs issue (double accumulator ping-pong).

typedef _Float16 f16;
typedef _Float16 f16x4 __attribute__((ext_vector_type(4)));
typedef _Float16 f16x8 __attribute__((ext_vector_type(8)));
typedef float    f32x4 __attribute__((ext_vector_type(4)));

#define B_   512
#define T_   200
#define E_   128
#define H_   128
#define G4_  512
#define M_   (B_*T_)   // 102400
#define LUTN 8192      // sigma table entries over [-16,16)

static __device__ __forceinline__ void lgkm_barrier() {
  asm volatile("s_waitcnt lgkmcnt(0)" ::: "memory");
  __builtin_amdgcn_s_barrier();
}

// ---------- prep: x fp32 -> f16 ----------
__global__ __launch_bounds__(256)
void cvt_x(const float* __restrict__ x, f16* __restrict__ xh) {
  const int n8 = M_ * E_ / 8;
  for (int i = blockIdx.x * 256 + threadIdx.x; i < n8; i += gridDim.x * 256) {
    const float4 a = ((const float4*)x)[i * 2];
    const float4 b = ((const float4*)x)[i * 2 + 1];
    f16x8 v;
    v[0] = (f16)a.x; v[1] = (f16)a.y; v[2] = (f16)a.z; v[3] = (f16)a.w;
    v[4] = (f16)b.x; v[5] = (f16)b.y; v[6] = (f16)b.z; v[7] = (f16)b.w;
    *(f16x8*)(xh + (size_t)i * 8) = v;
  }
}

// ---------- prep: W,U [slab][128][512] fp32 -> [slab][512][128] f16 ----------
// 8 slabs: 4 of W then 4 of U.  g-gate rows (cols 256..383) prescaled x2 so
// tanh(zg) = 2*sigma(zg') - 1 needs no extra multiply.
__global__ __launch_bounds__(256)
void prep_w(const float* __restrict__ W, const float* __restrict__ U,
            f16* __restrict__ Wt, f16* __restrict__ Ut) {
  const int m = blockIdx.x;                     // 0..7
  const float* s = (m < 4 ? W + (size_t)m * E_ * G4_ : U + (size_t)(m - 4) * E_ * G4_);
  f16* d        = (m < 4 ? Wt + (size_t)m * E_ * G4_ : Ut + (size_t)(m - 4) * E_ * G4_);
  for (int i = threadIdx.x; i < E_ * G4_; i += 256) {
    const int k = i >> 9, g = i & 511;
    float v = s[i];
    if ((g >> 7) == 2) v *= 2.f;
    d[(size_t)g * E_ + k] = (f16)v;
  }
}

// ---------- fused recurrent scan ----------
// grid 64: dir = bx>>5, rows [R0, R0+16).  block 512 = 8 waves.
// Wave wv owns gate-cols {g*128 + wv*16 + c}.  Lane l: batch row l&15,
// kg = l>>4, output cells kg*4+i of hidden slice [wv*16, wv*16+16).
template <int LAYER>
__global__ __launch_bounds__(512, 2)
void scan_fused(const f16* __restrict__ in,    // L0: xh [M][128]; L1: h0 [2][M][128]
                const f16* __restrict__ Utl,   // [2][512][128] this layer (transposed, g x2)
                const f16* __restrict__ Wtl,   // [2][512][128] this layer (transposed, g x2)
                const float* __restrict__ bl,  // [2][512] this layer (raw)
                const f16* __restrict__ res,   // L1: h0 [2][M][128]
                f16* __restrict__ hout)        // [2][M][128]
{
  __shared__ float lut[LUTN];
  __shared__ f16 hsh[2][16][136];

  const int tid  = threadIdx.x;
  const int lane = tid & 63;
  const int wv   = tid >> 6;
  const int row  = lane & 15;
  const int kg   = lane >> 4;
  const int bx   = blockIdx.x;
  const int dir  = bx >> 5;
  const int R0   = (bx & 31) * 16;
  const int coff = wv * 16 + kg * 4;

  const f16* Ud = Utl + (size_t)dir * G4_ * E_;
  const f16* Wd = Wtl + (size_t)dir * G4_ * E_;
  const float* bd = bl + (size_t)dir * G4_;
  const f16* ind  = in + (LAYER == 1 ? (size_t)dir * M_ * H_ : 0);
  f16* houtd      = hout + (size_t)dir * M_ * H_;

  // fill sigma LUT: lut[i] = sigma((i - LUTN/2) / 256)
  for (int i = tid; i < LUTN; i += 512) {
    const float xx = (float)(i - LUTN / 2) * (1.f / 256.f);
    lut[i] = 1.f / (1.f + expf(-xx));
  }
  // zero h(-1)
  for (int i = tid; i < 2 * 16 * 136; i += 512) ((f16*)hsh)[i] = (f16)0.f;

  // stationary A-frags (vector loads from pre-transposed f16)
  f16x8 aU[4][4], aW[4][4];
#pragma unroll
  for (int g = 0; g < 4; ++g) {
    const size_t gcol = (size_t)(g * 128 + wv * 16 + row) * E_;
#pragma unroll
    for (int kk = 0; kk < 4; ++kk) {
      aU[g][kk] = *(const f16x8*)(Ud + gcol + kk * 32 + kg * 8);
      aW[g][kk] = *(const f16x8*)(Wd + gcol + kk * 32 + kg * 8);
    }
  }
  // bias (g-gate x2 to match prescaled weights)
  f32x4 zb[4];
#pragma unroll
  for (int g = 0; g < 4; ++g) {
#pragma unroll
    for (int i = 0; i < 4; ++i) {
      const float v = bd[g * 128 + coff + i];
      zb[g][i] = (g == 2) ? 2.f * v : v;
    }
  }

  const int t0 = dir ? (T_ - 1) : 0;
  const int ts = dir ? -1 : 1;

  const f16* inrow  = ind + (size_t)(R0 + row) * T_ * E_;
  const f16* resrow = (LAYER == 1)
      ? res + (size_t)dir * M_ * H_ + (size_t)(R0 + row) * T_ * H_ : nullptr;
  f16* outrow = houtd + (size_t)(R0 + row) * T_ * H_;

  float cc[4] = {0.f, 0.f, 0.f, 0.f};

  // prologue loads: x(t0) (consumed below), x(t0+ts), x(t0+2ts)
  f16x8 xP[4], xA[4], xB[4];
  f16x4 rvA = {}, rvB = {};
#pragma unroll
  for (int kk = 0; kk < 4; ++kk) {
    xP[kk] = *(const f16x8*)(inrow + (long)t0 * E_ + kk * 32 + kg * 8);
    xA[kk] = *(const f16x8*)(inrow + (long)(t0 + ts) * E_ + kk * 32 + kg * 8);
    xB[kk] = *(const f16x8*)(inrow + (long)(t0 + 2 * ts) * E_ + kk * 32 + kg * 8);
  }
  if (LAYER == 1) {
    rvA = *(const f16x4*)(resrow + (long)t0 * H_ + coff);
    rvB = *(const f16x4*)(resrow + (long)(t0 + ts) * H_ + coff);
  }

  lgkm_barrier();   // lut + hsh-zero visible

  // zA = b + W*x(t0)
  f32x4 zA[4], zB[4];
#pragma unroll
  for (int g = 0; g < 4; ++g) zA[g] = zb[g];
#pragma unroll
  for (int kk = 0; kk < 4; ++kk) {
    zA[0] = __builtin_amdgcn_mfma_f32_16x16x32_f16(aW[0][kk], xP[kk], zA[0], 0, 0, 0);
    zA[1] = __builtin_amdgcn_mfma_f32_16x16x32_f16(aW[1][kk], xP[kk], zA[1], 0, 0, 0);
    zA[2] = __builtin_amdgcn_mfma_f32_16x16x32_f16(aW[2][kk], xP[kk], zA[2], 0, 0, 0);
    zA[3] = __builtin_amdgcn_mfma_f32_16x16x32_f16(aW[3][kk], xP[kk], zA[3], 0, 0, 0);
  }

  // step: complete zc(t) with U*h(t-1), run gates; meanwhile build
  // zn(t+1) = b + W*x(t+1) (h-independent; fills gate-phase bubbles).
  auto step = [&](f32x4 (&zc)[4], f32x4 (&zn)[4], f16x8 (&xn)[4], f16x4& rv,
                  int s, int rp, int wp) {
    const int t = t0 + s * ts;

    // h(t-1) from LDS
    f16x8 hf[4];
#pragma unroll
    for (int kk = 0; kk < 4; ++kk) hf[kk] = *(const f16x8*)&hsh[rp][row][kk * 32 + kg * 8];

    // zc += U*h(t-1)
#pragma unroll
    for (int kk = 0; kk < 4; ++kk) {
      zc[0] = __builtin_amdgcn_mfma_f32_16x16x32_f16(aU[0][kk], hf[kk], zc[0], 0, 0, 0);
      zc[1] = __builtin_amdgcn_mfma_f32_16x16x32_f16(aU[1][kk], hf[kk], zc[1], 0, 0, 0);
      zc[2] = __builtin_amdgcn_mfma_f32_16x16x32_f16(aU[2][kk], hf[kk], zc[2], 0, 0, 0);
      zc[3] = __builtin_amdgcn_mfma_f32_16x16x32_f16(aU[3][kk], hf[kk], zc[3], 0, 0, 0);
    }

    // build zn = b + W*x(t+1)  (independent of h)
#pragma unroll
    for (int g = 0; g < 4; ++g) zn[g] = zb[g];
#pragma unroll
    for (int kk = 0; kk < 4; ++kk) {
      zn[0] = __builtin_amdgcn_mfma_f32_16x16x32_f16(aW[0][kk], xn[kk], zn[0], 0, 0, 0);
      zn[1] = __builtin_amdgcn_mfma_f32_16x16x32_f16(aW[1][kk], xn[kk], zn[1], 0, 0, 0);
      zn[2] = __builtin_amdgcn_mfma_f32_16x16x32_f16(aW[2][kk], xn[kk], zn[2], 0, 0, 0);
      zn[3] = __builtin_amdgcn_mfma_f32_16x16x32_f16(aW[3][kk], xn[kk], zn[3], 0, 0, 0);
    }

    // reload xn <- x(t+3ts) (consumed at s+2; buffer padding makes OOB safe)
    {
      const f16* p = inrow + (long)(t + 3 * ts) * E_;
#pragma unroll
      for (int kk = 0; kk < 4; ++kk) xn[kk] = *(const f16x8*)(p + kk * 32 + kg * 8);
    }
    float rvf[4];
    if (LAYER == 1) {
#pragma unroll
      for (int i = 0; i < 4; ++i) rvf[i] = (float)rv[i];
      rv = *(const f16x4*)(resrow + (long)(t + 2 * ts) * H_ + coff);
    }

    // gates via sigma-LUT (all 5 nonlinearities)
    auto lidx = [](float u) -> int {
      u = fminf(fmaxf(u, 0.f), (float)(LUTN - 1));
      return (int)u;
    };
    float hv[4];
#pragma unroll
    for (int i = 0; i < 4; ++i) {
      const float ig = lut[lidx(fmaf(zc[0][i], 256.f, (float)(LUTN / 2)))];
      const float fg = lut[lidx(fmaf(zc[1][i], 256.f, (float)(LUTN / 2)))];
      const float gg = fmaf(2.f, lut[lidx(fmaf(zc[2][i], 256.f, (float)(LUTN / 2)))], -1.f);
      const float og = lut[lidx(fmaf(zc[3][i], 256.f, (float)(LUTN / 2)))];
      cc[i] = fg * cc[i] + ig * gg;
      const float th = fmaf(2.f, lut[lidx(fmaf(cc[i], 512.f, (float)(LUTN / 2)))], -1.f);
      hv[i] = og * th;
    }

    f16x4 hp;
#pragma unroll
    for (int i = 0; i < 4; ++i) hp[i] = (f16)hv[i];
    *(f16x4*)&hsh[wp][row][coff] = hp;

    f16* orow = outrow + (long)t * H_ + coff;
    if (LAYER == 0) {
      *(f16x4*)orow = hp;
    } else {
      f16x4 o;
#pragma unroll
      for (int i = 0; i < 4; ++i) o[i] = (f16)(0.5f * (hv[i] + rvf[i]));
      *(f16x4*)orow = o;
    }

    lgkm_barrier();   // h(t) visible; vmcnt NOT drained
  };

  for (int k = 0; k < T_ / 2; ++k) {
    step(zA, zB, xA, rvA, 2 * k,     0, 1);
    step(zB, zA, xB, rvB, 2 * k + 1, 1, 0);
  }
}

__global__ __launch_bounds__(256)
void final_add(const f16* __restrict__ a, const f16* __restrict__ b,
               float* __restrict__ o)
{
  const int n8 = M_ * H_ / 8;
  for (int i = blockIdx.x * 256 + threadIdx.x; i < n8; i += gridDim.x * 256) {
    const f16x8 va = *(const f16x8*)(a + (size_t)i * 8);
    const f16x8 vb = *(const f16x8*)(b + (size_t)i * 8);
    float4 o0, o1;
    o0.x = (float)va[0] + (float)vb[0];  o0.y = (float)va[1] + (float)vb[1];
    o0.z = (float)va[2] + (float)vb[2];  o0.w = (float)va[3] + (float)vb[3];
    o1.x = (float)va[4] + (float)vb[4];  o1.y = (float)va[5] + (float)vb[5];
    o1.z = (float)va[6] + (float)vb[6];  o1.w = (float)va[7] + (float)vb[7];
    *(float4*)(o + (size_t)i * 8)     = o0;
    *(float4*)(o + (size_t)i * 8 + 4) = o1;
  }
}

extern "C" void kernel_launch(void* const* d_in, const int* in_sizes, int n_in,
                              void* d_out, int out_size, void* d_ws, size_t ws_size,
                              hipStream_t stream) {
  const float* x = (const float*)d_in[0];
  const float* W = (const float*)d_in[1];  // [2][2][128][512]
  const float* U = (const float*)d_in[2];  // [2][2][128][512]
  const float* b = (const float*)d_in[3];  // [2][2][512]
  float* out = (float*)d_out;

  char* ws = (char*)d_ws;
  // 2KB front guard: bw-direction prefetch reads up to 3 timesteps (768B)
  // before the first row of xh.
  f16* xh = (f16*)(ws + 2048);                     // [M][128]    26.2 MB
  f16* h0 = xh + (size_t)M_ * E_;                  // [2][M][128] 52.4 MB
  f16* h1 = h0 + (size_t)2 * M_ * H_;              // [2][M][128] 52.4 MB
  f16* Wt = h1 + (size_t)2 * M_ * H_;              // [2][2][512][128] 1 MB
  f16* Ut = Wt + (size_t)4 * G4_ * E_;             // [2][2][512][128] 1 MB

  const size_t WTL = (size_t)2 * G4_ * E_;         // f16 per layer of Wt/Ut
  const size_t BL  = 2 * G4_;

  cvt_x<<<dim3(2048), 256, 0, stream>>>(x, xh);
  prep_w<<<dim3(8), 256, 0, stream>>>(W, U, Wt, Ut);
  scan_fused<0><<<dim3(64), 512, 0, stream>>>(xh, Ut, Wt, b, nullptr, h0);
  scan_fused<1><<<dim3(64), 512, 0, stream>>>(h0, Ut + WTL, Wt + WTL, b + BL, h0, h1);
  final_add<<<dim3(2048), 256, 0, stream>>>(h1, h1 + (size_t)M_ * H_, out);
}